// Round 2
// baseline (195.382 us; speedup 1.0000x reference)
//
#include <hip/hip_runtime.h>
#include <hip/hip_bf16.h>
#include <math.h>

#define NN 325
#define FD 64
#define KH 4
#define DH 16
#define BT 192
#define NN2 (NN*NN)
#define PST (NN*DH)     // 5200 elems per (proj,head,bt) slice
#define VTS  352        // vT row stride (bf16)
#define VSLICE (16*VTS) // vT per-(h,bt) slice
#define HSTR 72         // ffn LDS stride (bf16)
#define PLW 352         // attn P LDS row stride (bf16)
#define NPROJ 975
#define NBIAS 1848                       // 4*336*352 / 256 exactly
#define NPAD  (KH*BT)                    // 768
#define ANB   8064                       // attn blocks (2 waves each)
#define LOG2E 1.44269504088896f

typedef __attribute__((ext_vector_type(8))) short short8;
typedef __attribute__((ext_vector_type(4))) float f32x4;

union U8 { uint4 u; short8 s; ushort us[8]; };
__device__ inline short8 lds8(const ushort* p){ U8 t; t.u = *(const uint4*)p; return t.s; }
__device__ inline float b2f(ushort v){ return __uint_as_float(((unsigned)v) << 16); }
__device__ inline ushort f2b(float f){
  unsigned u = __float_as_uint(f);
  u += 0x7fff + ((u >> 16) & 1);
  return (ushort)(u >> 16);
}
__device__ inline unsigned pk2(float a, float b){
  union { __hip_bfloat162 h; unsigned u; } t;
  t.h = __float22bfloat162_rn(float2{a, b});
  return t.u;
}
__device__ inline short8 cvt8(const float* p){
  float4 u = ((const float4*)p)[0], v = ((const float4*)p)[1];
  U8 t;
  t.us[0]=f2b(u.x); t.us[1]=f2b(u.y); t.us[2]=f2b(u.z); t.us[3]=f2b(u.w);
  t.us[4]=f2b(v.x); t.us[5]=f2b(v.y); t.us[6]=f2b(v.z); t.us[7]=f2b(v.w);
  return t.s;
}

// ---------------- wpack: W's -> Wcat bf16 [448][64] + bcat + identity frags ----------------
__global__ __launch_bounds__(256) void wpack_kernel(
    const float* __restrict__ Wq,  const float* __restrict__ bq,
    const float* __restrict__ Wk,  const float* __restrict__ bk,
    const float* __restrict__ Wks, const float* __restrict__ bks,
    const float* __restrict__ Wv,  const float* __restrict__ bv,
    const float* __restrict__ Wvs, const float* __restrict__ bvs,
    const float* __restrict__ Wf1, const float* __restrict__ Wf2,
    ushort* __restrict__ Wcat, float* __restrict__ bcat,
    ushort* __restrict__ idT){
  int blk = blockIdx.x;
  if (blk == 7){
    // identity A-fragment table, replicated 21x for uniform ct stride:
    // idT[ct][l32][j] = (l32&15) == ((l32>>4)*8 + j) ? bf16(1.0) : 0
    for (int e = threadIdx.x; e < 672; e += 256){
      int l = e & 31, mm = l & 15, gg = l >> 4;
      U8 t;
      #pragma unroll
      for (int j = 0; j < 8; ++j) t.us[j] = (mm == gg*8 + j) ? (ushort)0x3F80 : (ushort)0;
      *(uint4*)(idT + (size_t)e*8) = t.u;
    }
    return;
  }
  const float* Ws[7] = {Wq, Wk, Wks, Wv, Wvs, Wf1, Wf2};
  const float* bs[5] = {bq, bk, bks, bv, bvs};
  int f = blk * 64 + (threadIdx.x >> 2);
  int c0 = (threadIdx.x & 3) * 8;
  const float* wr = Ws[blk] + (f & 63) * 64;
  unsigned* dst = (unsigned*)Wcat + f * 32 + c0;
  #pragma unroll
  for (int c = 0; c < 8; ++c)
    dst[c] = f2b(wr[2*(c0+c)]) | ((unsigned)f2b(wr[2*(c0+c)+1]) << 16);
  if (blk < 5 && (threadIdx.x & 3) == 0) bcat[f] = bs[blk][f & 63];
}

// ---------------- prep: proj (+V->vt direct) | bias bf16 [4][336][352] | vt pad zero ----------------
__global__ __launch_bounds__(256) void prep_kernel(
    const float* __restrict__ x, const ushort* __restrict__ Wcat,
    const float* __restrict__ bcat, ushort* __restrict__ proj,
    ushort* __restrict__ vt,
    const float* __restrict__ Wdi, const float* __restrict__ Wdo,
    const float* __restrict__ A,   const float* __restrict__ AT,
    ushort* __restrict__ biasB){
  int bid = blockIdx.x, tid = threadIdx.x;
  if (bid < NPROJ){
    // ---- projections via MFMA (A=W rows, B=x rows) ----
    int lane = tid & 63, wid = tid >> 6;
    int r0 = bid * 64 + wid * 16;
    int m = lane & 15, g = lane >> 4;
    int gr = r0 + m;
    int bt = gr / NN, n = gr - bt * NN;
    const float* xr = x + (size_t)gr * 64 + g * 8;
    short8 xb0 = cvt8(xr);
    short8 xb1 = cvt8(xr + 32);
    for (int ct = 0; ct < 20; ++ct){
      short8 w0 = lds8(Wcat + ((size_t)(ct*16 + m) * 64 + g * 8));
      short8 w1 = lds8(Wcat + ((size_t)(ct*16 + m) * 64 + g * 8 + 32));
      float4 b4 = *(const float4*)(bcat + ct*16 + 4*g);
      f32x4 acc = {b4.x, b4.y, b4.z, b4.w};
      acc = __builtin_amdgcn_mfma_f32_16x16x32_bf16(w0, xb0, acc, 0, 0, 0);
      acc = __builtin_amdgcn_mfma_f32_16x16x32_bf16(w1, xb1, acc, 0, 0, 0);
      if (ct >= 12 && ct < 16){
        // V head (ct-12): write transposed directly to vt[d][n]
        ushort* vs = vt + (size_t)((ct-12)*BT + bt) * VSLICE + n;
        #pragma unroll
        for (int rg = 0; rg < 4; ++rg)
          vs[(size_t)(4*g + rg) * VTS] = f2b(acc[rg]);
      } else {
        // fold 1/sqrt(D) AND log2(e) into Q (softmax runs on exp2)
        float sc = (ct < 4) ? 0.25f * LOG2E : 1.0f;
        uint2 w;
        w.x = pk2(acc[0]*sc, acc[1]*sc);
        w.y = pk2(acc[2]*sc, acc[3]*sc);
        *(uint2*)(proj + ((size_t)ct * BT + bt) * PST + n*16 + 4*g) = w;
      }
    }
  } else if (bid < NPROJ + NBIAS){
    // ---- bias bf16 [4][336][352], x log2e; pads = -1e30 (exp2 -> 0 mask) ----
    int idx = (bid - NPROJ) * 256 + tid;
    int h = idx / 118272;                 // 336*352
    int rem = idx - h * 118272;
    int n = rem / 352, mc = rem - n * 352;
    float s = -1e30f;
    if (n < NN && mc < NN){
      int r = n * NN + mc;
      s = 0.f;
      if (h < 2){
        #pragma unroll
        for (int k = 0; k < 3; ++k) s += Wdi[(h*3 + k)*NN2 + r] * A[k*NN2 + r];
      } else {
        int h2 = h - 2;
        #pragma unroll
        for (int k = 0; k < 3; ++k) s += Wdo[(h2*3 + k)*NN2 + r] * AT[k*NN2 + r];
      }
      s *= LOG2E;
    }
    biasB[idx] = f2b(s);
  } else {
    // ---- vt pad: zero cols 325..351 for one (h,bt) slice ----
    int slice = bid - NPROJ - NBIAS;
    ushort* vs = vt + (size_t)slice * VSLICE;
    if (tid < 432){
      int d = tid / 27, c = NN + tid % 27;
      vs[(size_t)d * VTS + c] = 0;
    }
  }
}

// ---------------- attention: one wave per tile; XCD-chunked; XOR-swizzled P LDS ----------------
// QK^T swapped (mfma(K,Q)); bias folded via identity A-half; softmax in-register.
// P LDS rows swizzled: col ^ ((m&7)<<3) for 128B-closed region [0,320),
// col ^ ((m&3)<<3) for the 64B row tail [320,352) — kills the phase-level
// 8-way bank conflicts of the 176-dword row stride.
__global__ __launch_bounds__(128, 4) void attn_kernel(
    const ushort* __restrict__ proj, const ushort* __restrict__ biasB,
    const ushort* __restrict__ idT, const ushort* __restrict__ vt,
    ushort* __restrict__ val){
  __shared__ __align__(16) ushort Pl[2][16*PLW];
  int tid = threadIdx.x, lane = tid & 63, wid = tid >> 6;
  int bid = (int)blockIdx.x;
  int swz = (bid & 7) * (ANB/8) + (bid >> 3);   // contiguous tile range per XCD
  int tile = swz * 2 + wid;                     // 8064*2 = 16128 = 4*192*21 tiles
  int qt = tile % 21, bh = tile / 21;
  int h = bh / BT, bt = bh - h * BT;
  int m = lane & 15, g = lane >> 4;
  int sxf = (m & 7) << 3, sxt = (m & 3) << 3;   // swizzles (ushort units)

  const ushort* qb  = proj + (size_t)((0*KH + h)*BT + bt) * PST;
  const ushort* kb  = proj + (size_t)((1*KH + h)*BT + bt) * PST;
  const ushort* ksb = proj + (size_t)((2*KH + h)*BT + bt) * PST;
  const ushort* vsb = proj + (size_t)((4*KH + h)*BT + bt) * PST;

  // -------- early prefetches: vT fragments + gate rows (latency hides under QK) --------
  const ushort* vtg = vt + (size_t)(h*BT + bt)*VSLICE + (size_t)m*VTS + g*8;
  short8 vf[11];
  #pragma unroll
  for (int tt = 0; tt < 8; ++tt) vf[tt] = lds8(vtg + tt*32);

  int nq = qt*16 + m, nb = min(nq, NN-1);
  uint2 qw = *(const uint2*)(qb + (size_t)nb*16 + g*4);
  uint2 kw = *(const uint2*)(ksb + (size_t)nb*16 + g*4);

  // A operand: g<2 -> K rows, g>=2 -> identity frags (uniform ct stride 256)
  const ushort* pa0 = (g < 2) ? (kb + m*16 + g*8) : (idT + (size_t)(lane & 31)*8);
  // B operand: g<2 -> Q row (ct-invariant), g>=2 -> bias frag (ct stride 16)
  const ushort* pb0 = (g < 2)
      ? (qb + (size_t)(qt*16 + m)*16 + g*8)
      : (biasB + (size_t)(h*336 + qt*16 + m)*352 + (g-2)*8);
  int bstep = (g < 2) ? 0 : 16;

  // -------- fused QK^T + bias + exp2 + pack-to-LDS (2-deep pipelined) --------
  ushort* Pw = &Pl[wid][m*PLW];
  float rowsum = 0.f;
  short8 zero = {0,0,0,0,0,0,0,0};
  short8 a0 = lds8(pa0),       b0 = lds8(pb0);
  short8 a1 = lds8(pa0 + 256), b1 = lds8(pb0 + bstep);
  #pragma unroll
  for (int ct = 0; ct < 21; ++ct){
    short8 a2 = zero, b2 = zero;
    if (ct + 2 < 21){ a2 = lds8(pa0 + (ct+2)*256); b2 = lds8(pb0 + (ct+2)*bstep); }
    f32x4 acc = {0.f, 0.f, 0.f, 0.f};
    acc = __builtin_amdgcn_mfma_f32_16x16x32_bf16(a0, b0, acc, 0, 0, 0);
    // acc[rg] = S'[tok=ct*16+g*4+rg][q=m] incl. bias, log2 domain
    float e0 = __builtin_amdgcn_exp2f(acc[0]);
    float e1 = __builtin_amdgcn_exp2f(acc[1]);
    float e2 = __builtin_amdgcn_exp2f(acc[2]);
    float e3 = __builtin_amdgcn_exp2f(acc[3]);
    rowsum += (e0 + e1) + (e2 + e3);
    uint2 w; w.x = pk2(e0, e1); w.y = pk2(e2, e3);
    int col = ct*16 + g*4;
    *(uint2*)(Pw + (col ^ (ct < 20 ? sxf : sxt))) = w;   // P[q=m][col..col+3]
    a0 = a1; b0 = b1; a1 = a2; b1 = b2;
  }
  { uint2 z; z.x = 0u; z.y = 0u; *(uint2*)(Pw + ((336 + g*4) ^ sxt)) = z; }

  // remaining vT fragments
  #pragma unroll
  for (int tt = 8; tt < 11; ++tt) vf[tt] = lds8(vtg + tt*32);

  // full row-m sum (lanes differ only in token subset across g)
  rowsum += __shfl_xor(rowsum, 16, 64);
  rowsum += __shfl_xor(rowsum, 32, 64);

  // sigmoid gate: dp = (q * 0.25*log2e) . ks over 16 dims (4 per g-lane)
  float dp = b2f((ushort)(qw.x & 0xffff)) * b2f((ushort)(kw.x & 0xffff))
           + b2f((ushort)(qw.x >> 16))    * b2f((ushort)(kw.x >> 16))
           + b2f((ushort)(qw.y & 0xffff)) * b2f((ushort)(kw.y & 0xffff))
           + b2f((ushort)(qw.y >> 16))    * b2f((ushort)(kw.y >> 16));
  dp += __shfl_xor(dp, 16, 64);
  dp += __shfl_xor(dp, 32, 64);
  float esv  = __builtin_amdgcn_rcpf(1.f + __builtin_amdgcn_exp2f(-dp));
  float inv  = __builtin_amdgcn_rcpf(esv + rowsum);
  float beta = 1.f - rowsum * inv;

  // wave-local LDS sync (cross-lane write->read within the wave)
  asm volatile("s_waitcnt lgkmcnt(0)" ::: "memory");

  // -------- PV: A = swizzled P rows from LDS, B = prefetched vT frags --------
  const ushort* Pr = &Pl[wid][m*PLW];
  f32x4 o = {0.f, 0.f, 0.f, 0.f};
  #pragma unroll
  for (int tt = 0; tt < 11; ++tt){
    int col = tt*32 + g*8;
    short8 pf = lds8(Pr + (col ^ (tt < 10 ? sxf : sxt)));
    o = __builtin_amdgcn_mfma_f32_16x16x32_bf16(pf, vf[tt], o, 0, 0, 0);
  }

  // redistribute row stats: lane (m,g) needs rows 4g+rg (held by lanes 0..15)
  int sb = g << 4;
  float invr[4], betr[4];
  #pragma unroll
  for (int rg = 0; rg < 4; ++rg){
    invr[rg] = __uint_as_float(__builtin_amdgcn_ds_bpermute(sb + rg*4, __float_as_uint(inv)));
    betr[rg] = __uint_as_float(__builtin_amdgcn_ds_bpermute(sb + rg*4, __float_as_uint(beta)));
  }
  #pragma unroll
  for (int rg = 0; rg < 4; ++rg){
    int n = qt*16 + 4*g + rg;
    int nc = min(n, NN-1);
    float vsx = b2f(vsb[(size_t)nc*16 + m]);
    float res = o[rg]*invr[rg] + betr[rg]*vsx;
    if (n < NN) val[((size_t)bt*NN + n)*FD + h*16 + m] = f2b(res);
  }
}

// ---------------- FFN + residual + LayerNorm (swapped operands, no barrier) ----------------
__global__ __launch_bounds__(256) void ffn_kernel(
    const ushort* __restrict__ val, const float* __restrict__ x,
    const ushort* __restrict__ Wf1b, const float* __restrict__ bf1,
    const ushort* __restrict__ Wf2b, const float* __restrict__ bf2,
    const float* __restrict__ g_ln, const float* __restrict__ b_ln,
    float* __restrict__ out){
  __shared__ ushort hs[4][16 * HSTR];   // wave-private slices
  int tid = threadIdx.x, lane = tid & 63, wid = tid >> 6;
  int m = lane & 15, g = lane >> 4;
  int r0 = blockIdx.x * 64 + wid * 16;
  int row = r0 + m;

  short8 vb0 = lds8(val + ((size_t)row * 64 + g * 8));
  short8 vb1 = lds8(val + ((size_t)row * 64 + g * 8 + 32));

  #pragma unroll
  for (int ct = 0; ct < 4; ++ct){
    short8 w0 = lds8(Wf1b + ((size_t)(ct*16 + m) * 64 + g * 8));
    short8 w1 = lds8(Wf1b + ((size_t)(ct*16 + m) * 64 + g * 8 + 32));
    float4 b4 = *(const float4*)(bf1 + ct*16 + 4*g);
    f32x4 acc = {b4.x, b4.y, b4.z, b4.w};
    acc = __builtin_amdgcn_mfma_f32_16x16x32_bf16(w0, vb0, acc, 0, 0, 0);
    acc = __builtin_amdgcn_mfma_f32_16x16x32_bf16(w1, vb1, acc, 0, 0, 0);
    uint2 w;
    float g0 = 0.5f*acc[0]*(1.f + erff(acc[0]*0.70710678118654752f));
    float g1 = 0.5f*acc[1]*(1.f + erff(acc[1]*0.70710678118654752f));
    float g2 = 0.5f*acc[2]*(1.f + erff(acc[2]*0.70710678118654752f));
    float g3 = 0.5f*acc[3]*(1.f + erff(acc[3]*0.70710678118654752f));
    w.x = pk2(g0, g1); w.y = pk2(g2, g3);
    *(uint2*)&hs[wid][m * HSTR + ct*16 + 4*g] = w;
  }
  asm volatile("s_waitcnt lgkmcnt(0)" ::: "memory");
  short8 h0 = lds8(&hs[wid][m * HSTR + g * 8]);
  short8 h1 = lds8(&hs[wid][m * HSTR + g * 8 + 32]);

  float t[4][4];
  #pragma unroll
  for (int ct = 0; ct < 4; ++ct){
    short8 w0 = lds8(Wf2b + ((size_t)(ct*16 + m) * 64 + g * 8));
    short8 w1 = lds8(Wf2b + ((size_t)(ct*16 + m) * 64 + g * 8 + 32));
    float4 b4 = *(const float4*)(bf2 + ct*16 + 4*g);
    f32x4 acc = {b4.x, b4.y, b4.z, b4.w};
    acc = __builtin_amdgcn_mfma_f32_16x16x32_bf16(w0, h0, acc, 0, 0, 0);
    acc = __builtin_amdgcn_mfma_f32_16x16x32_bf16(w1, h1, acc, 0, 0, 0);
    float4 xr = *(const float4*)(x + (size_t)row * 64 + ct*16 + 4*g);
    t[ct][0] = acc[0] + xr.x; t[ct][1] = acc[1] + xr.y;
    t[ct][2] = acc[2] + xr.z; t[ct][3] = acc[3] + xr.w;
  }
  float s = 0.f;
  #pragma unroll
  for (int ct = 0; ct < 4; ++ct) s += (t[ct][0]+t[ct][1]) + (t[ct][2]+t[ct][3]);
  s += __shfl_xor(s, 16, 64); s += __shfl_xor(s, 32, 64);
  float mu = s * (1.f/64.f);
  float v = 0.f;
  #pragma unroll
  for (int ct = 0; ct < 4; ++ct){
    #pragma unroll
    for (int rg = 0; rg < 4; ++rg){ float d = t[ct][rg] - mu; v += d*d; }
  }
  v += __shfl_xor(v, 16, 64); v += __shfl_xor(v, 32, 64);
  float rs = rsqrtf(v * (1.f/64.f) + 1e-5f);
  #pragma unroll
  for (int ct = 0; ct < 4; ++ct){
    float4 g4 = *(const float4*)(g_ln + ct*16 + 4*g);
    float4 bb = *(const float4*)(b_ln + ct*16 + 4*g);
    float4 o;
    o.x = g4.x*(t[ct][0]-mu)*rs + bb.x;
    o.y = g4.y*(t[ct][1]-mu)*rs + bb.y;
    o.z = g4.z*(t[ct][2]-mu)*rs + bb.z;
    o.w = g4.w*(t[ct][3]-mu)*rs + bb.w;
    *(float4*)(out + (size_t)row * 64 + ct*16 + 4*g) = o;
  }
}

extern "C" void kernel_launch(void* const* d_in, const int* in_sizes, int n_in,
                              void* d_out, int out_size, void* d_ws, size_t ws_size,
                              hipStream_t stream) {
  const float* x    = (const float*)d_in[0];
  const float* A    = (const float*)d_in[1];
  const float* AT   = (const float*)d_in[2];
  const float* Wq   = (const float*)d_in[3];
  const float* bq   = (const float*)d_in[4];
  const float* Wk   = (const float*)d_in[5];
  const float* bk   = (const float*)d_in[6];
  const float* Wks  = (const float*)d_in[7];
  const float* bks  = (const float*)d_in[8];
  const float* Wv   = (const float*)d_in[9];
  const float* bv   = (const float*)d_in[10];
  const float* Wvs  = (const float*)d_in[11];
  const float* bvs  = (const float*)d_in[12];
  const float* Wdi  = (const float*)d_in[13];
  const float* Wdo  = (const float*)d_in[14];
  const float* Wf1  = (const float*)d_in[15];
  const float* bf1  = (const float*)d_in[16];
  const float* Wf2  = (const float*)d_in[17];
  const float* bf2  = (const float*)d_in[18];
  const float* g_ln = (const float*)d_in[19];
  const float* b_ln = (const float*)d_in[20];
  float* out = (float*)d_out;

  float* ws = (float*)d_ws;
  ushort* proj  = (ushort*)ws;                     // bf16, 19,968,000 el (p=3 unused)
  ushort* biasB = (ushort*)(ws + 9984000);         // bf16, 473,088 el [4][336][352]
  ushort* idT   = biasB + 473088;                  // bf16, 5,376 el [21][32][8]
  ushort* val   = (ushort*)(ws + 10441600);        // bf16, 3,993,600 el
  ushort* vt    = (ushort*)(ws + 12438400);        // bf16, 4,325,376 el
  ushort* Wcat  = (ushort*)(ws + 14601088);        // bf16, 28,672 el
  float*  bcat  = ws + 14615424;                   // fp32, 320
  ushort* Wf1b  = Wcat + 320*64;
  ushort* Wf2b  = Wcat + 384*64;

  wpack_kernel<<<8, 256, 0, stream>>>(Wq, bq, Wk, bk, Wks, bks,
                                      Wv, bv, Wvs, bvs, Wf1, Wf2, Wcat, bcat, idT);
  prep_kernel<<<NPROJ + NBIAS + NPAD, 256, 0, stream>>>(
      x, Wcat, bcat, proj, vt, Wdi, Wdo, A, AT, biasB);
  attn_kernel<<<ANB, 128, 0, stream>>>(proj, biasB, idT, vt, val);
  ffn_kernel<<<975, 256, 0, stream>>>(val, x, Wf1b, bf1, Wf2b, bf2,
                                      g_ln, b_ln, out);
}

// Round 3
// 194.846 us; speedup vs baseline: 1.0027x; 1.0027x over previous
//
#include <hip/hip_runtime.h>
#include <hip/hip_bf16.h>
#include <math.h>

#define NN 325
#define FD 64
#define KH 4
#define DH 16
#define BT 192
#define NN2 (NN*NN)
#define PST (NN*DH)     // 5200 elems per (proj,head,bt) slice
#define VTS  352        // vT row stride (bf16)
#define VSLICE (16*VTS) // vT per-(h,bt) slice
#define HSTR 72         // ffn LDS stride (bf16)
#define NPROJ 975
#define NBIAS 1848                       // 4*336*352 / 256 exactly
#define NPAD  (KH*BT)                    // 768
#define ANB   4032                       // attn blocks (4 waves each)
#define LOG2E 1.44269504088896f

typedef __attribute__((ext_vector_type(8))) short short8;
typedef __attribute__((ext_vector_type(4))) float f32x4;

union U8 { uint4 u; short8 s; ushort us[8]; };
__device__ inline short8 lds8(const ushort* p){ U8 t; t.u = *(const uint4*)p; return t.s; }
__device__ inline float b2f(ushort v){ return __uint_as_float(((unsigned)v) << 16); }
__device__ inline ushort f2b(float f){
  unsigned u = __float_as_uint(f);
  u += 0x7fff + ((u >> 16) & 1);
  return (ushort)(u >> 16);
}
__device__ inline unsigned pk2(float a, float b){
  union { __hip_bfloat162 h; unsigned u; } t;
  t.h = __float22bfloat162_rn(float2{a, b});
  return t.u;
}
__device__ inline short8 cvt8(const float* p){
  float4 u = ((const float4*)p)[0], v = ((const float4*)p)[1];
  U8 t;
  t.us[0]=f2b(u.x); t.us[1]=f2b(u.y); t.us[2]=f2b(u.z); t.us[3]=f2b(u.w);
  t.us[4]=f2b(v.x); t.us[5]=f2b(v.y); t.us[6]=f2b(v.z); t.us[7]=f2b(v.w);
  return t.s;
}

// ---------------- wpack: W's -> Wcat bf16 [448][64] + bcat + identity frags ----------------
__global__ __launch_bounds__(256) void wpack_kernel(
    const float* __restrict__ Wq,  const float* __restrict__ bq,
    const float* __restrict__ Wk,  const float* __restrict__ bk,
    const float* __restrict__ Wks, const float* __restrict__ bks,
    const float* __restrict__ Wv,  const float* __restrict__ bv,
    const float* __restrict__ Wvs, const float* __restrict__ bvs,
    const float* __restrict__ Wf1, const float* __restrict__ Wf2,
    ushort* __restrict__ Wcat, float* __restrict__ bcat,
    ushort* __restrict__ idT){
  int blk = blockIdx.x;
  if (blk == 7){
    // identity A-fragment table: idT[l32][j] = (l32&15) == ((l32>>4)*8 + j) ? bf16(1.0) : 0
    for (int e = threadIdx.x; e < 672; e += 256){
      int l = e & 31, mm = l & 15, gg = l >> 4;
      U8 t;
      #pragma unroll
      for (int j = 0; j < 8; ++j) t.us[j] = (mm == gg*8 + j) ? (ushort)0x3F80 : (ushort)0;
      *(uint4*)(idT + (size_t)e*8) = t.u;
    }
    return;
  }
  const float* Ws[7] = {Wq, Wk, Wks, Wv, Wvs, Wf1, Wf2};
  const float* bs[5] = {bq, bk, bks, bv, bvs};
  int f = blk * 64 + (threadIdx.x >> 2);
  int c0 = (threadIdx.x & 3) * 8;
  const float* wr = Ws[blk] + (f & 63) * 64;
  unsigned* dst = (unsigned*)Wcat + f * 32 + c0;
  #pragma unroll
  for (int c = 0; c < 8; ++c)
    dst[c] = f2b(wr[2*(c0+c)]) | ((unsigned)f2b(wr[2*(c0+c)+1]) << 16);
  if (blk < 5 && (threadIdx.x & 3) == 0) bcat[f] = bs[blk][f & 63];
}

// ---------------- prep: proj (+V->vt direct) | permuted bias bf16 [4][336][352] | vt pad ----------------
__global__ __launch_bounds__(256) void prep_kernel(
    const float* __restrict__ x, const ushort* __restrict__ Wcat,
    const float* __restrict__ bcat, ushort* __restrict__ proj,
    ushort* __restrict__ vt,
    const float* __restrict__ Wdi, const float* __restrict__ Wdo,
    const float* __restrict__ A,   const float* __restrict__ AT,
    ushort* __restrict__ biasB){
  int bid = blockIdx.x, tid = threadIdx.x;
  if (bid < NPROJ){
    // ---- projections via MFMA (A=W rows, B=x rows) ----
    int lane = tid & 63, wid = tid >> 6;
    int r0 = bid * 64 + wid * 16;
    int m = lane & 15, g = lane >> 4;
    int gr = r0 + m;
    int bt = gr / NN, n = gr - bt * NN;
    const float* xr = x + (size_t)gr * 64 + g * 8;
    short8 xb0 = cvt8(xr);
    short8 xb1 = cvt8(xr + 32);
    for (int ct = 0; ct < 20; ++ct){
      short8 w0 = lds8(Wcat + ((size_t)(ct*16 + m) * 64 + g * 8));
      short8 w1 = lds8(Wcat + ((size_t)(ct*16 + m) * 64 + g * 8 + 32));
      float4 b4 = *(const float4*)(bcat + ct*16 + 4*g);
      f32x4 acc = {b4.x, b4.y, b4.z, b4.w};
      acc = __builtin_amdgcn_mfma_f32_16x16x32_bf16(w0, xb0, acc, 0, 0, 0);
      acc = __builtin_amdgcn_mfma_f32_16x16x32_bf16(w1, xb1, acc, 0, 0, 0);
      if (ct >= 12 && ct < 16){
        // V head (ct-12): write transposed directly to vt[d][n]
        ushort* vs = vt + (size_t)((ct-12)*BT + bt) * VSLICE + n;
        #pragma unroll
        for (int rg = 0; rg < 4; ++rg)
          vs[(size_t)(4*g + rg) * VTS] = f2b(acc[rg]);
      } else {
        // fold 1/sqrt(D) AND log2(e) into Q (softmax runs on exp2)
        float sc = (ct < 4) ? 0.25f * LOG2E : 1.0f;
        uint2 w;
        w.x = pk2(acc[0]*sc, acc[1]*sc);
        w.y = pk2(acc[2]*sc, acc[3]*sc);
        *(uint2*)(proj + ((size_t)ct * BT + bt) * PST + n*16 + 4*g) = w;
      }
    }
  } else if (bid < NPROJ + NBIAS){
    // ---- bias bf16 [4][336][352], PERMUTED col' = j*16+r -> token
    //      tok = 32*(j>>1) + 8*(r>>2) + 4*(j&1) + (r&3); x log2e; invalid -> -1e30 ----
    int idx = (bid - NPROJ) * 256 + tid;
    int h = idx / 118272;                 // 336*352
    int rem = idx - h * 118272;
    int n = rem / 352, mc = rem - n * 352;
    int j = mc >> 4, r = mc & 15;
    int tok = 32*(j>>1) + 8*(r>>2) + 4*(j&1) + (r&3);
    float s = -1e30f;
    if (n < NN && tok < NN){
      int ridx = n * NN + tok;
      s = 0.f;
      if (h < 2){
        #pragma unroll
        for (int k = 0; k < 3; ++k) s += Wdi[(h*3 + k)*NN2 + ridx] * A[k*NN2 + ridx];
      } else {
        int h2 = h - 2;
        #pragma unroll
        for (int k = 0; k < 3; ++k) s += Wdo[(h2*3 + k)*NN2 + ridx] * AT[k*NN2 + ridx];
      }
      s *= LOG2E;
    }
    biasB[idx] = f2b(s);
  } else {
    // ---- vt pad: zero cols 325..351 for one (h,bt) slice ----
    int slice = bid - NPROJ - NBIAS;
    ushort* vs = vt + (size_t)slice * VSLICE;
    if (tid < 432){
      int d = tid / 27, c = NN + tid % 27;
      vs[(size_t)d * VTS + c] = 0;
    }
  }
}

// ---------------- attention: one wave per tile, ZERO LDS, fully fused ----------------
// K tokens loaded permuted (row r <- token 32*tt + 8*(r>>2) + 4*half + (r&3)) so each
// lane's QK accumulators ARE its PV A-fragment: QK-even, QK-odd -> exp2 -> pack ->
// PV MFMA per 32-token window. P never leaves registers; bias folded via identity
// A-half with the pre-permuted bias table; out-of-range tokens masked by -1e30 bias.
__global__ __launch_bounds__(256, 4) void attn_kernel(
    const ushort* __restrict__ proj, const ushort* __restrict__ biasB,
    const ushort* __restrict__ idT, const ushort* __restrict__ vt,
    ushort* __restrict__ val){
  int tid = threadIdx.x, lane = tid & 63, wid = tid >> 6;
  int bid = (int)blockIdx.x;
  int swz = (bid & 7) * (ANB/8) + (bid >> 3);   // contiguous tile range per XCD
  int tile = swz * 4 + wid;                     // 4032*4 = 16128 = 4*192*21 tiles
  int qt = tile % 21, bh = tile / 21;
  int h = bh / BT, bt = bh - h * BT;
  int m = lane & 15, g = lane >> 4;
  int lext = 8*(m >> 2) + (m & 3);              // token offset of row m within a window-half

  const ushort* qb  = proj + (size_t)((0*KH + h)*BT + bt) * PST;
  const ushort* kb  = proj + (size_t)((1*KH + h)*BT + bt) * PST;
  const ushort* ksb = proj + (size_t)((2*KH + h)*BT + bt) * PST;
  const ushort* vsb = proj + (size_t)((4*KH + h)*BT + bt) * PST;

  // -------- vT prefetch (11 windows) --------
  const ushort* vtg = vt + (size_t)(h*BT + bt)*VSLICE + (size_t)m*VTS + g*8;
  short8 vf[11];
  #pragma unroll
  for (int tt = 0; tt < 11; ++tt) vf[tt] = lds8(vtg + tt*32);

  // -------- gate rows --------
  int nq = qt*16 + m, nb = min(nq, NN-1);
  uint2 qw = *(const uint2*)(qb + (size_t)nb*16 + g*4);
  uint2 kw = *(const uint2*)(ksb + (size_t)nb*16 + g*4);

  // A operand: g<2 -> K token rows (permuted, clamped), g>=2 -> identity frag (fixed addr)
  const ushort* abase = (g < 2) ? (kb + g*8) : (idT + (size_t)(lane & 31)*8);
  int amul = (g < 2) ? 16 : 0;
  // B operand: g<2 -> Q row (fixed), g>=2 -> permuted bias frag (stride 16/iter)
  const ushort* pbase = (g < 2)
      ? (qb + (size_t)(qt*16 + m)*16 + g*8)
      : (biasB + (size_t)(h*336 + qt*16 + m)*352 + (g-2)*8);
  int bstep = (g < 2) ? 0 : 16;

  short8 aE0 = lds8(abase + min(lext, 324)*amul);
  short8 aO0 = lds8(abase + min(lext + 4, 324)*amul);
  short8 bE0 = lds8(pbase);
  short8 bO0 = lds8(pbase + bstep);

  f32x4 o = {0.f, 0.f, 0.f, 0.f};
  float rowsum = 0.f;
  #pragma unroll
  for (int tt = 0; tt < 11; ++tt){
    short8 aE1 = aE0, aO1 = aO0, bE1 = bE0, bO1 = bO0;
    if (tt < 10){
      int wbase = 32*(tt+1);
      aE1 = lds8(abase + min(wbase + lext,     324)*amul);
      aO1 = lds8(abase + min(wbase + lext + 4, 324)*amul);
      bE1 = lds8(pbase + (2*tt+2)*bstep);
      bO1 = lds8(pbase + (2*tt+3)*bstep);
    }
    f32x4 accE = {0.f,0.f,0.f,0.f}, accO = {0.f,0.f,0.f,0.f};
    accE = __builtin_amdgcn_mfma_f32_16x16x32_bf16(aE0, bE0, accE, 0, 0, 0);
    accO = __builtin_amdgcn_mfma_f32_16x16x32_bf16(aO0, bO0, accO, 0, 0, 0);
    // lane (m,g): accE = P-tokens 32tt+8g+{0..3}, accO = +{4..7} (q = m), log2 domain
    float e0 = __builtin_amdgcn_exp2f(accE[0]);
    float e1 = __builtin_amdgcn_exp2f(accE[1]);
    float e2 = __builtin_amdgcn_exp2f(accE[2]);
    float e3 = __builtin_amdgcn_exp2f(accE[3]);
    float e4 = __builtin_amdgcn_exp2f(accO[0]);
    float e5 = __builtin_amdgcn_exp2f(accO[1]);
    float e6 = __builtin_amdgcn_exp2f(accO[2]);
    float e7 = __builtin_amdgcn_exp2f(accO[3]);
    rowsum += ((e0 + e1) + (e2 + e3)) + ((e4 + e5) + (e6 + e7));
    U8 pf;
    pf.u.x = pk2(e0, e1);
    pf.u.y = pk2(e2, e3);
    pf.u.z = pk2(e4, e5);
    pf.u.w = pk2(e6, e7);
    o = __builtin_amdgcn_mfma_f32_16x16x32_bf16(pf.s, vf[tt], o, 0, 0, 0);
    aE0 = aE1; aO0 = aO1; bE0 = bE1; bO0 = bO1;
  }

  // full q-row sum (lanes with same m hold disjoint token subsets across g)
  rowsum += __shfl_xor(rowsum, 16, 64);
  rowsum += __shfl_xor(rowsum, 32, 64);

  // sigmoid gate: dp = (q * 0.25*log2e) . ks over 16 dims (4 per g-lane)
  float dp = b2f((ushort)(qw.x & 0xffff)) * b2f((ushort)(kw.x & 0xffff))
           + b2f((ushort)(qw.x >> 16))    * b2f((ushort)(kw.x >> 16))
           + b2f((ushort)(qw.y & 0xffff)) * b2f((ushort)(kw.y & 0xffff))
           + b2f((ushort)(qw.y >> 16))    * b2f((ushort)(kw.y >> 16));
  dp += __shfl_xor(dp, 16, 64);
  dp += __shfl_xor(dp, 32, 64);
  float esv  = __builtin_amdgcn_rcpf(1.f + __builtin_amdgcn_exp2f(-dp));
  float inv  = __builtin_amdgcn_rcpf(esv + rowsum);
  float beta = 1.f - rowsum * inv;

  // redistribute row stats: lane (m,g) needs rows 4g+rg (held by lanes 0..15)
  int sb = g << 4;
  float invr[4], betr[4];
  #pragma unroll
  for (int rg = 0; rg < 4; ++rg){
    invr[rg] = __uint_as_float(__builtin_amdgcn_ds_bpermute(sb + rg*4, __float_as_uint(inv)));
    betr[rg] = __uint_as_float(__builtin_amdgcn_ds_bpermute(sb + rg*4, __float_as_uint(beta)));
  }
  #pragma unroll
  for (int rg = 0; rg < 4; ++rg){
    int n = qt*16 + 4*g + rg;
    int nc = min(n, NN-1);
    float vsx = b2f(vsb[(size_t)nc*16 + m]);
    float res = o[rg]*invr[rg] + betr[rg]*vsx;
    if (n < NN) val[((size_t)bt*NN + n)*FD + h*16 + m] = f2b(res);
  }
}

// ---------------- FFN + residual + LayerNorm (swapped operands, no barrier) ----------------
__global__ __launch_bounds__(256) void ffn_kernel(
    const ushort* __restrict__ val, const float* __restrict__ x,
    const ushort* __restrict__ Wf1b, const float* __restrict__ bf1,
    const ushort* __restrict__ Wf2b, const float* __restrict__ bf2,
    const float* __restrict__ g_ln, const float* __restrict__ b_ln,
    float* __restrict__ out){
  __shared__ ushort hs[4][16 * HSTR];   // wave-private slices
  int tid = threadIdx.x, lane = tid & 63, wid = tid >> 6;
  int m = lane & 15, g = lane >> 4;
  int r0 = blockIdx.x * 64 + wid * 16;
  int row = r0 + m;

  short8 vb0 = lds8(val + ((size_t)row * 64 + g * 8));
  short8 vb1 = lds8(val + ((size_t)row * 64 + g * 8 + 32));

  #pragma unroll
  for (int ct = 0; ct < 4; ++ct){
    short8 w0 = lds8(Wf1b + ((size_t)(ct*16 + m) * 64 + g * 8));
    short8 w1 = lds8(Wf1b + ((size_t)(ct*16 + m) * 64 + g * 8 + 32));
    float4 b4 = *(const float4*)(bf1 + ct*16 + 4*g);
    f32x4 acc = {b4.x, b4.y, b4.z, b4.w};
    acc = __builtin_amdgcn_mfma_f32_16x16x32_bf16(w0, vb0, acc, 0, 0, 0);
    acc = __builtin_amdgcn_mfma_f32_16x16x32_bf16(w1, vb1, acc, 0, 0, 0);
    uint2 w;
    float g0 = 0.5f*acc[0]*(1.f + erff(acc[0]*0.70710678118654752f));
    float g1 = 0.5f*acc[1]*(1.f + erff(acc[1]*0.70710678118654752f));
    float g2 = 0.5f*acc[2]*(1.f + erff(acc[2]*0.70710678118654752f));
    float g3 = 0.5f*acc[3]*(1.f + erff(acc[3]*0.70710678118654752f));
    w.x = pk2(g0, g1); w.y = pk2(g2, g3);
    *(uint2*)&hs[wid][m * HSTR + ct*16 + 4*g] = w;
  }
  asm volatile("s_waitcnt lgkmcnt(0)" ::: "memory");
  short8 h0 = lds8(&hs[wid][m * HSTR + g * 8]);
  short8 h1 = lds8(&hs[wid][m * HSTR + g * 8 + 32]);

  float t[4][4];
  #pragma unroll
  for (int ct = 0; ct < 4; ++ct){
    short8 w0 = lds8(Wf2b + ((size_t)(ct*16 + m) * 64 + g * 8));
    short8 w1 = lds8(Wf2b + ((size_t)(ct*16 + m) * 64 + g * 8 + 32));
    float4 b4 = *(const float4*)(bf2 + ct*16 + 4*g);
    f32x4 acc = {b4.x, b4.y, b4.z, b4.w};
    acc = __builtin_amdgcn_mfma_f32_16x16x32_bf16(w0, h0, acc, 0, 0, 0);
    acc = __builtin_amdgcn_mfma_f32_16x16x32_bf16(w1, h1, acc, 0, 0, 0);
    float4 xr = *(const float4*)(x + (size_t)row * 64 + ct*16 + 4*g);
    t[ct][0] = acc[0] + xr.x; t[ct][1] = acc[1] + xr.y;
    t[ct][2] = acc[2] + xr.z; t[ct][3] = acc[3] + xr.w;
  }
  float s = 0.f;
  #pragma unroll
  for (int ct = 0; ct < 4; ++ct) s += (t[ct][0]+t[ct][1]) + (t[ct][2]+t[ct][3]);
  s += __shfl_xor(s, 16, 64); s += __shfl_xor(s, 32, 64);
  float mu = s * (1.f/64.f);
  float v = 0.f;
  #pragma unroll
  for (int ct = 0; ct < 4; ++ct){
    #pragma unroll
    for (int rg = 0; rg < 4; ++rg){ float d = t[ct][rg] - mu; v += d*d; }
  }
  v += __shfl_xor(v, 16, 64); v += __shfl_xor(v, 32, 64);
  float rs = rsqrtf(v * (1.f/64.f) + 1e-5f);
  #pragma unroll
  for (int ct = 0; ct < 4; ++ct){
    float4 g4 = *(const float4*)(g_ln + ct*16 + 4*g);
    float4 bb = *(const float4*)(b_ln + ct*16 + 4*g);
    float4 o;
    o.x = g4.x*(t[ct][0]-mu)*rs + bb.x;
    o.y = g4.y*(t[ct][1]-mu)*rs + bb.y;
    o.z = g4.z*(t[ct][2]-mu)*rs + bb.z;
    o.w = g4.w*(t[ct][3]-mu)*rs + bb.w;
    *(float4*)(out + (size_t)row * 64 + ct*16 + 4*g) = o;
  }
}

extern "C" void kernel_launch(void* const* d_in, const int* in_sizes, int n_in,
                              void* d_out, int out_size, void* d_ws, size_t ws_size,
                              hipStream_t stream) {
  const float* x    = (const float*)d_in[0];
  const float* A    = (const float*)d_in[1];
  const float* AT   = (const float*)d_in[2];
  const float* Wq   = (const float*)d_in[3];
  const float* bq   = (const float*)d_in[4];
  const float* Wk   = (const float*)d_in[5];
  const float* bk   = (const float*)d_in[6];
  const float* Wks  = (const float*)d_in[7];
  const float* bks  = (const float*)d_in[8];
  const float* Wv   = (const float*)d_in[9];
  const float* bv   = (const float*)d_in[10];
  const float* Wvs  = (const float*)d_in[11];
  const float* bvs  = (const float*)d_in[12];
  const float* Wdi  = (const float*)d_in[13];
  const float* Wdo  = (const float*)d_in[14];
  const float* Wf1  = (const float*)d_in[15];
  const float* bf1  = (const float*)d_in[16];
  const float* Wf2  = (const float*)d_in[17];
  const float* bf2  = (const float*)d_in[18];
  const float* g_ln = (const float*)d_in[19];
  const float* b_ln = (const float*)d_in[20];
  float* out = (float*)d_out;

  float* ws = (float*)d_ws;
  ushort* proj  = (ushort*)ws;                     // bf16, 19,968,000 el (p=3 unused)
  ushort* biasB = (ushort*)(ws + 9984000);         // bf16, 473,088 el [4][336][352] permuted
  ushort* idT   = biasB + 473088;                  // bf16, 5,376 el
  ushort* val   = (ushort*)(ws + 10441600);        // bf16, 3,993,600 el
  ushort* vt    = (ushort*)(ws + 12438400);        // bf16, 4,325,376 el
  ushort* Wcat  = (ushort*)(ws + 14601088);        // bf16, 28,672 el
  float*  bcat  = ws + 14615424;                   // fp32, 320
  ushort* Wf1b  = Wcat + 320*64;
  ushort* Wf2b  = Wcat + 384*64;

  wpack_kernel<<<8, 256, 0, stream>>>(Wq, bq, Wk, bk, Wks, bks,
                                      Wv, bv, Wvs, bvs, Wf1, Wf2, Wcat, bcat, idT);
  prep_kernel<<<NPROJ + NBIAS + NPAD, 256, 0, stream>>>(
      x, Wcat, bcat, proj, vt, Wdi, Wdo, A, AT, biasB);
  attn_kernel<<<ANB, 256, 0, stream>>>(proj, biasB, idT, vt, val);
  ffn_kernel<<<975, 256, 0, stream>>>(val, x, Wf1b, bf1, Wf2b, bf2,
                                      g_ln, b_ln, out);
}

// Round 4
// 190.036 us; speedup vs baseline: 1.0281x; 1.0253x over previous
//
#include <hip/hip_runtime.h>
#include <hip/hip_bf16.h>
#include <math.h>

#define NN 325
#define FD 64
#define KH 4
#define DH 16
#define BT 192
#define NN2 (NN*NN)
#define PST (NN*DH)     // 5200 elems per (proj,head,bt) slice
#define WSL 5632        // per (h,bt) window slice: 11 windows * 512 el
#define HSTR 72         // ffn LDS stride (bf16)
#define NPROJ 975
#define NBIAS 1848                       // 4*21*11*16*32 / 256 exactly
#define NPAD  (KH*BT)                    // 768
#define ANB   4032                       // attn blocks (4 waves each)
#define LOG2E 1.44269504088896f

typedef __attribute__((ext_vector_type(8))) short short8;
typedef __attribute__((ext_vector_type(4))) float f32x4;

union U8 { uint4 u; short8 s; ushort us[8]; };
__device__ inline short8 lds8(const ushort* p){ U8 t; t.u = *(const uint4*)p; return t.s; }
__device__ inline float b2f(ushort v){ return __uint_as_float(((unsigned)v) << 16); }
__device__ inline ushort f2b(float f){
  unsigned u = __float_as_uint(f);
  u += 0x7fff + ((u >> 16) & 1);
  return (ushort)(u >> 16);
}
__device__ inline unsigned pk2(float a, float b){
  union { __hip_bfloat162 h; unsigned u; } t;
  t.h = __float22bfloat162_rn(float2{a, b});
  return t.u;
}
__device__ inline short8 cvt8(const float* p){
  float4 u = ((const float4*)p)[0], v = ((const float4*)p)[1];
  U8 t;
  t.us[0]=f2b(u.x); t.us[1]=f2b(u.y); t.us[2]=f2b(u.z); t.us[3]=f2b(u.w);
  t.us[4]=f2b(v.x); t.us[5]=f2b(v.y); t.us[6]=f2b(v.z); t.us[7]=f2b(v.w);
  return t.s;
}

// ---------------- wpack: W's -> Wcat bf16 [448][64] + bcat ----------------
__global__ __launch_bounds__(256) void wpack_kernel(
    const float* __restrict__ Wq,  const float* __restrict__ bq,
    const float* __restrict__ Wk,  const float* __restrict__ bk,
    const float* __restrict__ Wks, const float* __restrict__ bks,
    const float* __restrict__ Wv,  const float* __restrict__ bv,
    const float* __restrict__ Wvs, const float* __restrict__ bvs,
    const float* __restrict__ Wf1, const float* __restrict__ Wf2,
    ushort* __restrict__ Wcat, float* __restrict__ bcat){
  int blk = blockIdx.x;
  const float* Ws[7] = {Wq, Wk, Wks, Wv, Wvs, Wf1, Wf2};
  const float* bs[5] = {bq, bk, bks, bv, bvs};
  int f = blk * 64 + (threadIdx.x >> 2);
  int c0 = (threadIdx.x & 3) * 8;
  const float* wr = Ws[blk] + (f & 63) * 64;
  unsigned* dst = (unsigned*)Wcat + f * 32 + c0;
  #pragma unroll
  for (int c = 0; c < 8; ++c)
    dst[c] = f2b(wr[2*(c0+c)]) | ((unsigned)f2b(wr[2*(c0+c)+1]) << 16);
  if (blk < 5 && (threadIdx.x & 3) == 0) bcat[f] = bs[blk][f & 63];
}

// ---------------- prep ----------------
// proj slots: Q 0-3 (scaled), KS 4-7, VS 8-11. K -> kperm [h][bt][tt][half][r16][d16]
// with token(r,half) = 8*(r>>2)+4*half+(r&3) (bit2<->bit3 swap of window offset);
// V -> vt [h][bt][tt][d16][w32]; bias bf16 [h][qt][tt][m16][w32] x log2e, invalid = -1e30.
__global__ __launch_bounds__(256) void prep_kernel(
    const float* __restrict__ x, const ushort* __restrict__ Wcat,
    const float* __restrict__ bcat, ushort* __restrict__ proj,
    ushort* __restrict__ vt, ushort* __restrict__ kperm,
    const float* __restrict__ Wdi, const float* __restrict__ Wdo,
    const float* __restrict__ A,   const float* __restrict__ AT,
    ushort* __restrict__ biasB){
  int bid = blockIdx.x, tid = threadIdx.x;
  if (bid < NPROJ){
    // ---- projections via MFMA (A=W rows, B=x rows) ----
    int lane = tid & 63, wid = tid >> 6;
    int r0 = bid * 64 + wid * 16;
    int m = lane & 15, g = lane >> 4;
    int gr = r0 + m;
    int bt = gr / NN, n = gr - bt * NN;
    const float* xr = x + (size_t)gr * 64 + g * 8;
    short8 xb0 = cvt8(xr);
    short8 xb1 = cvt8(xr + 32);
    for (int ct = 0; ct < 20; ++ct){
      short8 w0 = lds8(Wcat + ((size_t)(ct*16 + m) * 64 + g * 8));
      short8 w1 = lds8(Wcat + ((size_t)(ct*16 + m) * 64 + g * 8 + 32));
      float4 b4 = *(const float4*)(bcat + ct*16 + 4*g);
      f32x4 acc = {b4.x, b4.y, b4.z, b4.w};
      acc = __builtin_amdgcn_mfma_f32_16x16x32_bf16(w0, xb0, acc, 0, 0, 0);
      acc = __builtin_amdgcn_mfma_f32_16x16x32_bf16(w1, xb1, acc, 0, 0, 0);
      if (ct >= 4 && ct < 8){
        // K head (ct-4): permuted window layout
        int w = n & 31;
        ushort* kd = kperm + (size_t)((ct-4)*BT + bt) * WSL
                   + (n >> 5)*512 + ((w >> 2) & 1)*256
                   + (4*(w >> 3) + (w & 3))*16 + 4*g;
        uint2 wv; wv.x = pk2(acc[0], acc[1]); wv.y = pk2(acc[2], acc[3]);
        *(uint2*)kd = wv;
      } else if (ct >= 12 && ct < 16){
        // V head (ct-12): vt[tt][d][w]
        ushort* vs = vt + (size_t)((ct-12)*BT + bt) * WSL + (n >> 5)*512 + (n & 31);
        #pragma unroll
        for (int rg = 0; rg < 4; ++rg)
          vs[(4*g + rg) * 32] = f2b(acc[rg]);
      } else {
        int slot = (ct < 4) ? ct : (ct < 12 ? ct - 4 : ct - 8);
        float sc = (ct < 4) ? 0.25f * LOG2E : 1.0f;
        uint2 w2;
        w2.x = pk2(acc[0]*sc, acc[1]*sc);
        w2.y = pk2(acc[2]*sc, acc[3]*sc);
        *(uint2*)(proj + ((size_t)slot * BT + bt) * PST + n*16 + 4*g) = w2;
      }
    }
  } else if (bid < NPROJ + NBIAS){
    // ---- bias bf16 [h][qt][tt][m][w] x log2e; invalid -> -1e30 (exp2 -> 0 mask) ----
    int idx = (bid - NPROJ) * 256 + tid;
    int h = idx / 118272;                  // 21*11*16*32
    int rem = idx - h * 118272;
    int qt = rem / 5632;
    int r2 = rem - qt * 5632;
    int tt = r2 >> 9, r3 = r2 & 511;
    int mq = r3 >> 5, w = r3 & 31;
    int n = qt*16 + mq;
    int tok = tt*32 + w;
    float s = -1e30f;
    if (n < NN && tok < NN){
      int ridx = n * NN + tok;
      s = 0.f;
      if (h < 2){
        #pragma unroll
        for (int k = 0; k < 3; ++k) s += Wdi[(h*3 + k)*NN2 + ridx] * A[k*NN2 + ridx];
      } else {
        int h2 = h - 2;
        #pragma unroll
        for (int k = 0; k < 3; ++k) s += Wdo[(h2*3 + k)*NN2 + ridx] * AT[k*NN2 + ridx];
      }
      s *= LOG2E;
    }
    biasB[idx] = f2b(s);
  } else {
    // ---- pad: zero tokens 325..351 (tt=10, w=5..31) in vt AND kperm ----
    int slice = bid - NPROJ - NBIAS;
    if (tid < 432){
      int d = tid / 27, wz = 5 + tid % 27;
      vt[(size_t)slice * WSL + 5120 + d*32 + wz] = 0;
      int half = (wz >> 2) & 1, rr = 4*(wz >> 3) + (wz & 3);
      kperm[(size_t)slice * WSL + 5120 + half*256 + rr*16 + d] = 0;
    }
  }
}

// ---------------- attention: one wave per tile, zero LDS, coalesced streams ----------------
// All per-window loads are contiguous: K 512B (4 lines), bias 1KB (8 lines), vT 1KB
// (8 lines), immediate-offset addressed. Bias added post-MFMA in fp32 (no identity
// trick); Q's k>=16 half zeroed once so the unused A-half contributes 0.
__global__ __launch_bounds__(256, 4) void attn_kernel(
    const ushort* __restrict__ proj, const ushort* __restrict__ biasB,
    const ushort* __restrict__ vt, const ushort* __restrict__ kperm,
    ushort* __restrict__ val){
  int tid = threadIdx.x, lane = tid & 63, wid = tid >> 6;
  int bid = (int)blockIdx.x;
  int swz = (bid & 7) * (ANB/8) + (bid >> 3);   // contiguous tile range per XCD
  int tile = swz * 4 + wid;                     // 4032*4 = 16128 = 4*192*21 tiles
  int qt = tile % 21, bh = tile / 21;
  int h = bh / BT, bt = bh - h * BT;
  int m = lane & 15, g = lane >> 4;

  const ushort* qb  = proj + (size_t)((0*KH + h)*BT + bt) * PST;
  const ushort* ksb = proj + (size_t)((1*KH + h)*BT + bt) * PST;
  const ushort* vsb = proj + (size_t)((2*KH + h)*BT + bt) * PST;
  const ushort* kpb = kperm + (size_t)(h*BT + bt) * WSL;
  const ushort* vtb = vt    + (size_t)(h*BT + bt) * WSL;
  const ushort* bbb = biasB + (size_t)(h*21 + qt) * WSL;

  short8 zero = {0,0,0,0,0,0,0,0};
  // Q fragment (once). g>=2 -> zero so the k>=16 A-half contributes nothing.
  short8 qf = (g < 2) ? lds8(qb + (size_t)(qt*16 + m)*16 + (g&1)*8) : zero;

  // per-lane stream bases (walk by +512 per window, imm-offset friendly)
  const ushort* ka = kpb + m*16 + (g&1)*8;
  const ushort* ba = bbb + m*32 + g*8;
  const ushort* va = vtb + m*32 + g*8;

  // gate rows
  int nq = qt*16 + m, nb = min(nq, NN-1);
  uint2 qw = *(const uint2*)(qb + (size_t)nb*16 + g*4);
  uint2 kw = *(const uint2*)(ksb + (size_t)nb*16 + g*4);

  // depth-2 pipeline
  short8 aE[2], aO[2], bf[2], vf[2];
  aE[0] = lds8(ka);       aO[0] = lds8(ka + 256);
  bf[0] = lds8(ba);       vf[0] = lds8(va);
  aE[1] = lds8(ka + 512); aO[1] = lds8(ka + 768);
  bf[1] = lds8(ba + 512); vf[1] = lds8(va + 512);

  f32x4 o = {0.f, 0.f, 0.f, 0.f};
  float rowsum = 0.f;
  #pragma unroll
  for (int tt = 0; tt < 11; ++tt){
    const int cur = tt & 1;
    short8 aEc = aE[cur], aOc = aO[cur], bfc = bf[cur], vfc = vf[cur];
    if (tt + 2 < 11){
      aE[cur] = lds8(ka + (tt+2)*512);
      aO[cur] = lds8(ka + (tt+2)*512 + 256);
      bf[cur] = lds8(ba + (tt+2)*512);
      vf[cur] = lds8(va + (tt+2)*512);
    }
    f32x4 accE = {0.f,0.f,0.f,0.f}, accO = {0.f,0.f,0.f,0.f};
    accE = __builtin_amdgcn_mfma_f32_16x16x32_bf16(aEc, qf, accE, 0, 0, 0);
    accO = __builtin_amdgcn_mfma_f32_16x16x32_bf16(aOc, qf, accO, 0, 0, 0);
    // lane (m,g): accE = S[tok 32tt+8g+{0..3}][q=m], accO = +{4..7}; add bias, exp2
    U8 bu; bu.s = bfc;
    float e0 = __builtin_amdgcn_exp2f(accE[0] + b2f(bu.us[0]));
    float e1 = __builtin_amdgcn_exp2f(accE[1] + b2f(bu.us[1]));
    float e2 = __builtin_amdgcn_exp2f(accE[2] + b2f(bu.us[2]));
    float e3 = __builtin_amdgcn_exp2f(accE[3] + b2f(bu.us[3]));
    float e4 = __builtin_amdgcn_exp2f(accO[0] + b2f(bu.us[4]));
    float e5 = __builtin_amdgcn_exp2f(accO[1] + b2f(bu.us[5]));
    float e6 = __builtin_amdgcn_exp2f(accO[2] + b2f(bu.us[6]));
    float e7 = __builtin_amdgcn_exp2f(accO[3] + b2f(bu.us[7]));
    rowsum += ((e0 + e1) + (e2 + e3)) + ((e4 + e5) + (e6 + e7));
    U8 pf;
    pf.u.x = pk2(e0, e1);
    pf.u.y = pk2(e2, e3);
    pf.u.z = pk2(e4, e5);
    pf.u.w = pk2(e6, e7);
    o = __builtin_amdgcn_mfma_f32_16x16x32_bf16(pf.s, vfc, o, 0, 0, 0);
  }

  // full q-row sum (lanes with same m hold disjoint token subsets across g)
  rowsum += __shfl_xor(rowsum, 16, 64);
  rowsum += __shfl_xor(rowsum, 32, 64);

  // sigmoid gate: dp = (q * 0.25*log2e) . ks over 16 dims (4 per g-lane)
  float dp = b2f((ushort)(qw.x & 0xffff)) * b2f((ushort)(kw.x & 0xffff))
           + b2f((ushort)(qw.x >> 16))    * b2f((ushort)(kw.x >> 16))
           + b2f((ushort)(qw.y & 0xffff)) * b2f((ushort)(kw.y & 0xffff))
           + b2f((ushort)(qw.y >> 16))    * b2f((ushort)(kw.y >> 16));
  dp += __shfl_xor(dp, 16, 64);
  dp += __shfl_xor(dp, 32, 64);
  float esv  = __builtin_amdgcn_rcpf(1.f + __builtin_amdgcn_exp2f(-dp));
  float inv  = __builtin_amdgcn_rcpf(esv + rowsum);
  float beta = 1.f - rowsum * inv;

  // redistribute row stats: lane (m,g) needs rows 4g+rg (held by lanes 0..15)
  int sb = g << 4;
  float invr[4], betr[4];
  #pragma unroll
  for (int rg = 0; rg < 4; ++rg){
    invr[rg] = __uint_as_float(__builtin_amdgcn_ds_bpermute(sb + rg*4, __float_as_uint(inv)));
    betr[rg] = __uint_as_float(__builtin_amdgcn_ds_bpermute(sb + rg*4, __float_as_uint(beta)));
  }
  #pragma unroll
  for (int rg = 0; rg < 4; ++rg){
    int n = qt*16 + 4*g + rg;
    int nc = min(n, NN-1);
    float vsx = b2f(vsb[(size_t)nc*16 + m]);
    float res = o[rg]*invr[rg] + betr[rg]*vsx;
    if (n < NN) val[((size_t)bt*NN + n)*FD + h*16 + m] = f2b(res);
  }
}

// ---------------- FFN + residual + LayerNorm (swapped operands, no barrier) ----------------
__global__ __launch_bounds__(256) void ffn_kernel(
    const ushort* __restrict__ val, const float* __restrict__ x,
    const ushort* __restrict__ Wf1b, const float* __restrict__ bf1,
    const ushort* __restrict__ Wf2b, const float* __restrict__ bf2,
    const float* __restrict__ g_ln, const float* __restrict__ b_ln,
    float* __restrict__ out){
  __shared__ ushort hs[4][16 * HSTR];   // wave-private slices
  int tid = threadIdx.x, lane = tid & 63, wid = tid >> 6;
  int m = lane & 15, g = lane >> 4;
  int r0 = blockIdx.x * 64 + wid * 16;
  int row = r0 + m;

  short8 vb0 = lds8(val + ((size_t)row * 64 + g * 8));
  short8 vb1 = lds8(val + ((size_t)row * 64 + g * 8 + 32));

  #pragma unroll
  for (int ct = 0; ct < 4; ++ct){
    short8 w0 = lds8(Wf1b + ((size_t)(ct*16 + m) * 64 + g * 8));
    short8 w1 = lds8(Wf1b + ((size_t)(ct*16 + m) * 64 + g * 8 + 32));
    float4 b4 = *(const float4*)(bf1 + ct*16 + 4*g);
    f32x4 acc = {b4.x, b4.y, b4.z, b4.w};
    acc = __builtin_amdgcn_mfma_f32_16x16x32_bf16(w0, vb0, acc, 0, 0, 0);
    acc = __builtin_amdgcn_mfma_f32_16x16x32_bf16(w1, vb1, acc, 0, 0, 0);
    uint2 w;
    float g0 = 0.5f*acc[0]*(1.f + erff(acc[0]*0.70710678118654752f));
    float g1 = 0.5f*acc[1]*(1.f + erff(acc[1]*0.70710678118654752f));
    float g2 = 0.5f*acc[2]*(1.f + erff(acc[2]*0.70710678118654752f));
    float g3 = 0.5f*acc[3]*(1.f + erff(acc[3]*0.70710678118654752f));
    w.x = pk2(g0, g1); w.y = pk2(g2, g3);
    *(uint2*)&hs[wid][m * HSTR + ct*16 + 4*g] = w;
  }
  asm volatile("s_waitcnt lgkmcnt(0)" ::: "memory");
  short8 h0 = lds8(&hs[wid][m * HSTR + g * 8]);
  short8 h1 = lds8(&hs[wid][m * HSTR + g * 8 + 32]);

  float t[4][4];
  #pragma unroll
  for (int ct = 0; ct < 4; ++ct){
    short8 w0 = lds8(Wf2b + ((size_t)(ct*16 + m) * 64 + g * 8));
    short8 w1 = lds8(Wf2b + ((size_t)(ct*16 + m) * 64 + g * 8 + 32));
    float4 b4 = *(const float4*)(bf2 + ct*16 + 4*g);
    f32x4 acc = {b4.x, b4.y, b4.z, b4.w};
    acc = __builtin_amdgcn_mfma_f32_16x16x32_bf16(w0, h0, acc, 0, 0, 0);
    acc = __builtin_amdgcn_mfma_f32_16x16x32_bf16(w1, h1, acc, 0, 0, 0);
    float4 xr = *(const float4*)(x + (size_t)row * 64 + ct*16 + 4*g);
    t[ct][0] = acc[0] + xr.x; t[ct][1] = acc[1] + xr.y;
    t[ct][2] = acc[2] + xr.z; t[ct][3] = acc[3] + xr.w;
  }
  float s = 0.f;
  #pragma unroll
  for (int ct = 0; ct < 4; ++ct) s += (t[ct][0]+t[ct][1]) + (t[ct][2]+t[ct][3]);
  s += __shfl_xor(s, 16, 64); s += __shfl_xor(s, 32, 64);
  float mu = s * (1.f/64.f);
  float v = 0.f;
  #pragma unroll
  for (int ct = 0; ct < 4; ++ct){
    #pragma unroll
    for (int rg = 0; rg < 4; ++rg){ float d = t[ct][rg] - mu; v += d*d; }
  }
  v += __shfl_xor(v, 16, 64); v += __shfl_xor(v, 32, 64);
  float rs = rsqrtf(v * (1.f/64.f) + 1e-5f);
  #pragma unroll
  for (int ct = 0; ct < 4; ++ct){
    float4 g4 = *(const float4*)(g_ln + ct*16 + 4*g);
    float4 bb = *(const float4*)(b_ln + ct*16 + 4*g);
    float4 o;
    o.x = g4.x*(t[ct][0]-mu)*rs + bb.x;
    o.y = g4.y*(t[ct][1]-mu)*rs + bb.y;
    o.z = g4.z*(t[ct][2]-mu)*rs + bb.z;
    o.w = g4.w*(t[ct][3]-mu)*rs + bb.w;
    *(float4*)(out + (size_t)row * 64 + ct*16 + 4*g) = o;
  }
}

extern "C" void kernel_launch(void* const* d_in, const int* in_sizes, int n_in,
                              void* d_out, int out_size, void* d_ws, size_t ws_size,
                              hipStream_t stream) {
  const float* x    = (const float*)d_in[0];
  const float* A    = (const float*)d_in[1];
  const float* AT   = (const float*)d_in[2];
  const float* Wq   = (const float*)d_in[3];
  const float* bq   = (const float*)d_in[4];
  const float* Wk   = (const float*)d_in[5];
  const float* bk   = (const float*)d_in[6];
  const float* Wks  = (const float*)d_in[7];
  const float* bks  = (const float*)d_in[8];
  const float* Wv   = (const float*)d_in[9];
  const float* bv   = (const float*)d_in[10];
  const float* Wvs  = (const float*)d_in[11];
  const float* bvs  = (const float*)d_in[12];
  const float* Wdi  = (const float*)d_in[13];
  const float* Wdo  = (const float*)d_in[14];
  const float* Wf1  = (const float*)d_in[15];
  const float* bf1  = (const float*)d_in[16];
  const float* Wf2  = (const float*)d_in[17];
  const float* bf2  = (const float*)d_in[18];
  const float* g_ln = (const float*)d_in[19];
  const float* b_ln = (const float*)d_in[20];
  float* out = (float*)d_out;

  float* ws = (float*)d_ws;
  ushort* proj  = (ushort*)ws;                     // 12 slots (Q0-3,KS4-7,VS8-11): 11,980,800 ush
  ushort* biasB = (ushort*)(ws + 5990400);         // 473,088 ush [4][21][11][16][32]
  ushort* val   = (ushort*)(ws + 6226944);         // 3,993,600 ush
  ushort* vt    = (ushort*)(ws + 8223744);         // 4,325,376 ush [4][192][11][16][32]
  ushort* kperm = (ushort*)(ws + 10386432);        // 4,325,376 ush [4][192][11][2][16][16]
  ushort* Wcat  = (ushort*)(ws + 12549120);        // 28,672 ush
  float*  bcat  = ws + 12563456;                   // 320 f
  ushort* Wf1b  = Wcat + 320*64;
  ushort* Wf2b  = Wcat + 384*64;

  wpack_kernel<<<7, 256, 0, stream>>>(Wq, bq, Wk, bk, Wks, bks,
                                      Wv, bv, Wvs, bvs, Wf1, Wf2, Wcat, bcat);
  prep_kernel<<<NPROJ + NBIAS + NPAD, 256, 0, stream>>>(
      x, Wcat, bcat, proj, vt, kperm, Wdi, Wdo, A, AT, biasB);
  attn_kernel<<<ANB, 256, 0, stream>>>(proj, biasB, vt, kperm, val);
  ffn_kernel<<<975, 256, 0, stream>>>(val, x, Wf1b, bf1, Wf2b, bf2,
                                      g_ln, b_ln, out);
}

// Round 5
// 188.612 us; speedup vs baseline: 1.0359x; 1.0075x over previous
//
#include <hip/hip_runtime.h>
#include <hip/hip_bf16.h>
#include <math.h>

#define NN 325
#define FD 64
#define KH 4
#define DH 16
#define BT 192
#define NN2 (NN*NN)
#define PST (NN*DH)     // 5200 elems per (proj,head,bt) slice
#define WSL 5632        // per (h,bt) window slice: 11 windows * 512 el (also biasF slice)
#define HSTR 72         // ffn LDS stride (bf16)
#define NPROJ 975
#define NBIAS 1848                       // 4*21*11*512 / 256 exactly
#define NPAD  (KH*BT)                    // 768
#define ANB   2112                       // attn blocks (4 waves each, 8448 waves)
#define LOG2E 1.44269504088896f

typedef __attribute__((ext_vector_type(8))) short short8;
typedef __attribute__((ext_vector_type(4))) float f32x4;

union U8 { uint4 u; short8 s; ushort us[8]; };
__device__ inline short8 lds8(const ushort* p){ U8 t; t.u = *(const uint4*)p; return t.s; }
__device__ inline float b2f(ushort v){ return __uint_as_float(((unsigned)v) << 16); }
__device__ inline ushort f2b(float f){
  unsigned u = __float_as_uint(f);
  u += 0x7fff + ((u >> 16) & 1);
  return (ushort)(u >> 16);
}
__device__ inline unsigned pk2(float a, float b){
  union { __hip_bfloat162 h; unsigned u; } t;
  t.h = __float22bfloat162_rn(float2{a, b});
  return t.u;
}
__device__ inline short8 cvt8(const float* p){
  float4 u = ((const float4*)p)[0], v = ((const float4*)p)[1];
  U8 t;
  t.us[0]=f2b(u.x); t.us[1]=f2b(u.y); t.us[2]=f2b(u.z); t.us[3]=f2b(u.w);
  t.us[4]=f2b(v.x); t.us[5]=f2b(v.y); t.us[6]=f2b(v.z); t.us[7]=f2b(v.w);
  return t.s;
}

// ---------------- wpack: W's -> Wcat bf16 [448][64] + bcat ----------------
__global__ __launch_bounds__(256) void wpack_kernel(
    const float* __restrict__ Wq,  const float* __restrict__ bq,
    const float* __restrict__ Wk,  const float* __restrict__ bk,
    const float* __restrict__ Wks, const float* __restrict__ bks,
    const float* __restrict__ Wv,  const float* __restrict__ bv,
    const float* __restrict__ Wvs, const float* __restrict__ bvs,
    const float* __restrict__ Wf1, const float* __restrict__ Wf2,
    ushort* __restrict__ Wcat, float* __restrict__ bcat){
  int blk = blockIdx.x;
  const float* Ws[7] = {Wq, Wk, Wks, Wv, Wvs, Wf1, Wf2};
  const float* bs[5] = {bq, bk, bks, bv, bvs};
  int f = blk * 64 + (threadIdx.x >> 2);
  int c0 = (threadIdx.x & 3) * 8;
  const float* wr = Ws[blk] + (f & 63) * 64;
  unsigned* dst = (unsigned*)Wcat + f * 32 + c0;
  #pragma unroll
  for (int c = 0; c < 8; ++c)
    dst[c] = f2b(wr[2*(c0+c)]) | ((unsigned)f2b(wr[2*(c0+c)+1]) << 16);
  if (blk < 5 && (threadIdx.x & 3) == 0) bcat[f] = bs[blk][f & 63];
}

// ---------------- prep ----------------
// proj slots: Q 0-3 (scaled), KS 4-7, VS 8-11. K -> kperm [h][bt][tt][half][r16][d16]
// (token(r,half) = 8*(r>>2)+4*half+(r&3)); V -> vt [h][bt][tt][d16][w32];
// bias fp32 in MFMA C-lane layout: biasF [h][qt][tt][g4][m16][e8], value =
// bias[q=qt*16+m][tok=tt*32+g*8+e8] * log2e, invalid -> -1e30 (exp2 -> 0 mask).
__global__ __launch_bounds__(256) void prep_kernel(
    const float* __restrict__ x, const ushort* __restrict__ Wcat,
    const float* __restrict__ bcat, ushort* __restrict__ proj,
    ushort* __restrict__ vt, ushort* __restrict__ kperm,
    const float* __restrict__ Wdi, const float* __restrict__ Wdo,
    const float* __restrict__ A,   const float* __restrict__ AT,
    float* __restrict__ biasF){
  int bid = blockIdx.x, tid = threadIdx.x;
  if (bid < NPROJ){
    // ---- projections via MFMA (A=W rows, B=x rows) ----
    int lane = tid & 63, wid = tid >> 6;
    int r0 = bid * 64 + wid * 16;
    int m = lane & 15, g = lane >> 4;
    int gr = r0 + m;
    int bt = gr / NN, n = gr - bt * NN;
    const float* xr = x + (size_t)gr * 64 + g * 8;
    short8 xb0 = cvt8(xr);
    short8 xb1 = cvt8(xr + 32);
    for (int ct = 0; ct < 20; ++ct){
      short8 w0 = lds8(Wcat + ((size_t)(ct*16 + m) * 64 + g * 8));
      short8 w1 = lds8(Wcat + ((size_t)(ct*16 + m) * 64 + g * 8 + 32));
      float4 b4 = *(const float4*)(bcat + ct*16 + 4*g);
      f32x4 acc = {b4.x, b4.y, b4.z, b4.w};
      acc = __builtin_amdgcn_mfma_f32_16x16x32_bf16(w0, xb0, acc, 0, 0, 0);
      acc = __builtin_amdgcn_mfma_f32_16x16x32_bf16(w1, xb1, acc, 0, 0, 0);
      if (ct >= 4 && ct < 8){
        // K head (ct-4): permuted window layout
        int w = n & 31;
        ushort* kd = kperm + (size_t)((ct-4)*BT + bt) * WSL
                   + (n >> 5)*512 + ((w >> 2) & 1)*256
                   + (4*(w >> 3) + (w & 3))*16 + 4*g;
        uint2 wv; wv.x = pk2(acc[0], acc[1]); wv.y = pk2(acc[2], acc[3]);
        *(uint2*)kd = wv;
      } else if (ct >= 12 && ct < 16){
        // V head (ct-12): vt[tt][d][w]
        ushort* vs = vt + (size_t)((ct-12)*BT + bt) * WSL + (n >> 5)*512 + (n & 31);
        #pragma unroll
        for (int rg = 0; rg < 4; ++rg)
          vs[(4*g + rg) * 32] = f2b(acc[rg]);
      } else {
        int slot = (ct < 4) ? ct : (ct < 12 ? ct - 4 : ct - 8);
        float sc = (ct < 4) ? 0.25f * LOG2E : 1.0f;
        uint2 w2;
        w2.x = pk2(acc[0]*sc, acc[1]*sc);
        w2.y = pk2(acc[2]*sc, acc[3]*sc);
        *(uint2*)(proj + ((size_t)slot * BT + bt) * PST + n*16 + 4*g) = w2;
      }
    }
  } else if (bid < NPROJ + NBIAS){
    // ---- bias fp32 C-lane layout; invalid -> -1e30 ----
    int idx = (bid - NPROJ) * 256 + tid;
    int h = idx / 118272;                  // 21*5632
    int rem = idx - h * 118272;
    int qt = rem / 5632;
    int r2 = rem - qt * 5632;
    int tt = r2 >> 9, r3 = r2 & 511;
    int gg = r3 >> 7, mm = (r3 >> 3) & 15, e8 = r3 & 7;
    int n = qt*16 + mm;
    int tok = tt*32 + gg*8 + e8;
    float s = -1e30f;
    if (n < NN && tok < NN){
      int ridx = n * NN + tok;
      s = 0.f;
      if (h < 2){
        #pragma unroll
        for (int k = 0; k < 3; ++k) s += Wdi[(h*3 + k)*NN2 + ridx] * A[k*NN2 + ridx];
      } else {
        int h2 = h - 2;
        #pragma unroll
        for (int k = 0; k < 3; ++k) s += Wdo[(h2*3 + k)*NN2 + ridx] * AT[k*NN2 + ridx];
      }
      s *= LOG2E;
    }
    biasF[idx] = s;
  } else {
    // ---- pad: zero tokens 325..351 (tt=10, w=5..31) in vt AND kperm ----
    int slice = bid - NPROJ - NBIAS;
    if (tid < 432){
      int d = tid / 27, wz = 5 + tid % 27;
      vt[(size_t)slice * WSL + 5120 + d*32 + wz] = 0;
      int half = (wz >> 2) & 1, rr = 4*(wz >> 3) + (wz & 3);
      kperm[(size_t)slice * WSL + 5120 + half*256 + rr*16 + d] = 0;
    }
  }
}

// ---------------- attention: one wave per 2 q-tiles of one (h,bt); zero LDS ----------------
// K/vT streams shared by both tiles; bias enters as the MFMA C-operand (fp32, lane
// layout); rowsum computed by an extra MFMA against a ones-fragment, which lands
// per-lane at exactly the q-rows (4g+rg) the epilogue needs — no shuffles for it.
__global__ __launch_bounds__(256, 3) void attn_kernel(
    const ushort* __restrict__ proj, const float* __restrict__ biasF,
    const ushort* __restrict__ vt, const ushort* __restrict__ kperm,
    ushort* __restrict__ val){
  int tid = threadIdx.x, lane = tid & 63, wid = tid >> 6;
  int bid = (int)blockIdx.x;
  int swz = (bid & 7) * (ANB/8) + (bid >> 3);   // contiguous range per XCD (2112%8==0)
  int p = swz * 4 + wid;                        // 8448 = 4*192*11 pair-slots
  int j = p % 11, bh = p / 11;
  int h = bh / BT, bt = bh - h * BT;
  int qt1 = 2*j;
  int two = (j < 10);
  int qt2 = two ? qt1 + 1 : qt1;                // j==10: qt=20 solo (redundant 2nd tile)
  int m = lane & 15, g = lane >> 4;

  const ushort* qb  = proj + (size_t)((0*KH + h)*BT + bt) * PST;
  const ushort* ksb = proj + (size_t)((1*KH + h)*BT + bt) * PST;
  const ushort* vsb = proj + (size_t)((2*KH + h)*BT + bt) * PST;
  const ushort* ka  = kperm + (size_t)(h*BT + bt) * WSL + m*16 + (g&1)*8;
  const ushort* va  = vt    + (size_t)(h*BT + bt) * WSL + m*32 + g*8;
  const float*  b1a = biasF + (size_t)(h*21 + qt1) * WSL + g*128 + m*8;
  const float*  b2a = biasF + (size_t)(h*21 + qt2) * WSL + g*128 + m*8;

  short8 zero = {0,0,0,0,0,0,0,0};
  // Q fragments; g>=2 zero so the k>=16 half of the QK MFMA contributes nothing
  short8 qf1 = (g < 2) ? lds8(qb + (size_t)(qt1*16 + m)*16 + (g&1)*8) : zero;
  short8 qf2 = (g < 2) ? lds8(qb + (size_t)(qt2*16 + m)*16 + (g&1)*8) : zero;

  // gate row loads issued early (dp math deferred to after the loop)
  int nb1 = min(qt1*16 + m, NN-1), nb2 = min(qt2*16 + m, NN-1);
  uint2 qw1 = *(const uint2*)(qb  + (size_t)nb1*16 + g*4);
  uint2 kw1 = *(const uint2*)(ksb + (size_t)nb1*16 + g*4);
  uint2 qw2 = *(const uint2*)(qb  + (size_t)nb2*16 + g*4);
  uint2 kw2 = *(const uint2*)(ksb + (size_t)nb2*16 + g*4);

  // rotating depth-1 prefetch
  short8 kE = lds8(ka), kO = lds8(ka + 256), vv = lds8(va);
  f32x4 bE1 = *(const f32x4*)(b1a), bO1 = *(const f32x4*)(b1a + 4);
  f32x4 bE2 = *(const f32x4*)(b2a), bO2 = *(const f32x4*)(b2a + 4);

  short8 ones = {16256,16256,16256,16256,16256,16256,16256,16256}; // bf16 1.0 x8
  f32x4 o1 = {0.f,0.f,0.f,0.f}, o2 = {0.f,0.f,0.f,0.f};
  f32x4 r1 = {0.f,0.f,0.f,0.f}, r2 = {0.f,0.f,0.f,0.f};

  #pragma unroll
  for (int tt = 0; tt < 11; ++tt){
    short8 kEn = zero, kOn = zero, vvn = zero;
    f32x4 bE1n = bE1, bO1n = bO1, bE2n = bE2, bO2n = bO2;
    if (tt < 10){
      const ushort* kan = ka + (tt+1)*512;
      kEn  = lds8(kan); kOn = lds8(kan + 256);
      vvn  = lds8(va + (tt+1)*512);
      bE1n = *(const f32x4*)(b1a + (tt+1)*512);
      bO1n = *(const f32x4*)(b1a + (tt+1)*512 + 4);
      bE2n = *(const f32x4*)(b2a + (tt+1)*512);
      bO2n = *(const f32x4*)(b2a + (tt+1)*512 + 4);
    }
    // tile 1: S + bias via C-operand, exp2, pack, PV + rowsum
    f32x4 aE1 = __builtin_amdgcn_mfma_f32_16x16x32_bf16(kE, qf1, bE1, 0, 0, 0);
    f32x4 aO1 = __builtin_amdgcn_mfma_f32_16x16x32_bf16(kO, qf1, bO1, 0, 0, 0);
    float e0 = __builtin_amdgcn_exp2f(aE1[0]);
    float e1 = __builtin_amdgcn_exp2f(aE1[1]);
    float e2 = __builtin_amdgcn_exp2f(aE1[2]);
    float e3 = __builtin_amdgcn_exp2f(aE1[3]);
    float e4 = __builtin_amdgcn_exp2f(aO1[0]);
    float e5 = __builtin_amdgcn_exp2f(aO1[1]);
    float e6 = __builtin_amdgcn_exp2f(aO1[2]);
    float e7 = __builtin_amdgcn_exp2f(aO1[3]);
    U8 p1;
    p1.u.x = pk2(e0, e1); p1.u.y = pk2(e2, e3);
    p1.u.z = pk2(e4, e5); p1.u.w = pk2(e6, e7);
    o1 = __builtin_amdgcn_mfma_f32_16x16x32_bf16(p1.s, vv,   o1, 0, 0, 0);
    r1 = __builtin_amdgcn_mfma_f32_16x16x32_bf16(p1.s, ones, r1, 0, 0, 0);
    // tile 2 (independent stream)
    f32x4 aE2 = __builtin_amdgcn_mfma_f32_16x16x32_bf16(kE, qf2, bE2, 0, 0, 0);
    f32x4 aO2 = __builtin_amdgcn_mfma_f32_16x16x32_bf16(kO, qf2, bO2, 0, 0, 0);
    float f0 = __builtin_amdgcn_exp2f(aE2[0]);
    float f1 = __builtin_amdgcn_exp2f(aE2[1]);
    float f2 = __builtin_amdgcn_exp2f(aE2[2]);
    float f3 = __builtin_amdgcn_exp2f(aE2[3]);
    float f4 = __builtin_amdgcn_exp2f(aO2[0]);
    float f5 = __builtin_amdgcn_exp2f(aO2[1]);
    float f6 = __builtin_amdgcn_exp2f(aO2[2]);
    float f7 = __builtin_amdgcn_exp2f(aO2[3]);
    U8 p2;
    p2.u.x = pk2(f0, f1); p2.u.y = pk2(f2, f3);
    p2.u.z = pk2(f4, f5); p2.u.w = pk2(f6, f7);
    o2 = __builtin_amdgcn_mfma_f32_16x16x32_bf16(p2.s, vv,   o2, 0, 0, 0);
    r2 = __builtin_amdgcn_mfma_f32_16x16x32_bf16(p2.s, ones, r2, 0, 0, 0);
    kE = kEn; kO = kOn; vv = vvn;
    bE1 = bE1n; bO1 = bO1n; bE2 = bE2n; bO2 = bO2n;
  }

  // ---- gate: dp per q=m, redistribute to q=4g+rg, sigmoid ----
  float dp1 = b2f((ushort)(qw1.x & 0xffff)) * b2f((ushort)(kw1.x & 0xffff))
            + b2f((ushort)(qw1.x >> 16))    * b2f((ushort)(kw1.x >> 16))
            + b2f((ushort)(qw1.y & 0xffff)) * b2f((ushort)(kw1.y & 0xffff))
            + b2f((ushort)(qw1.y >> 16))    * b2f((ushort)(kw1.y >> 16));
  float dp2 = b2f((ushort)(qw2.x & 0xffff)) * b2f((ushort)(kw2.x & 0xffff))
            + b2f((ushort)(qw2.x >> 16))    * b2f((ushort)(kw2.x >> 16))
            + b2f((ushort)(qw2.y & 0xffff)) * b2f((ushort)(kw2.y & 0xffff))
            + b2f((ushort)(qw2.y >> 16))    * b2f((ushort)(kw2.y >> 16));
  dp1 += __shfl_xor(dp1, 16, 64); dp1 += __shfl_xor(dp1, 32, 64);
  dp2 += __shfl_xor(dp2, 16, 64); dp2 += __shfl_xor(dp2, 32, 64);
  int sb = g << 4;
  #pragma unroll
  for (int rg = 0; rg < 4; ++rg){
    float d1 = __uint_as_float(__builtin_amdgcn_ds_bpermute(sb + rg*4, __float_as_uint(dp1)));
    float d2 = __uint_as_float(__builtin_amdgcn_ds_bpermute(sb + rg*4, __float_as_uint(dp2)));
    float es1 = __builtin_amdgcn_rcpf(1.f + __builtin_amdgcn_exp2f(-d1));
    float es2 = __builtin_amdgcn_rcpf(1.f + __builtin_amdgcn_exp2f(-d2));
    int n1 = qt1*16 + 4*g + rg;
    int n2 = qt2*16 + 4*g + rg;
    float vsx1 = b2f(vsb[(size_t)min(n1, NN-1)*16 + m]);
    float vsx2 = b2f(vsb[(size_t)min(n2, NN-1)*16 + m]);
    // out = (o + es*vs) / (es + rowsum)
    float iv1 = __builtin_amdgcn_rcpf(es1 + r1[rg]);
    float res1 = (o1[rg] + es1 * vsx1) * iv1;
    if (n1 < NN) val[((size_t)bt*NN + n1)*FD + h*16 + m] = f2b(res1);
    if (two){
      float iv2 = __builtin_amdgcn_rcpf(es2 + r2[rg]);
      float res2 = (o2[rg] + es2 * vsx2) * iv2;
      if (n2 < NN) val[((size_t)bt*NN + n2)*FD + h*16 + m] = f2b(res2);
    }
  }
}

// ---------------- FFN + residual + LayerNorm (swapped operands, no barrier) ----------------
__global__ __launch_bounds__(256) void ffn_kernel(
    const ushort* __restrict__ val, const float* __restrict__ x,
    const ushort* __restrict__ Wf1b, const float* __restrict__ bf1,
    const ushort* __restrict__ Wf2b, const float* __restrict__ bf2,
    const float* __restrict__ g_ln, const float* __restrict__ b_ln,
    float* __restrict__ out){
  __shared__ ushort hs[4][16 * HSTR];   // wave-private slices
  int tid = threadIdx.x, lane = tid & 63, wid = tid >> 6;
  int m = lane & 15, g = lane >> 4;
  int r0 = blockIdx.x * 64 + wid * 16;
  int row = r0 + m;

  short8 vb0 = lds8(val + ((size_t)row * 64 + g * 8));
  short8 vb1 = lds8(val + ((size_t)row * 64 + g * 8 + 32));

  #pragma unroll
  for (int ct = 0; ct < 4; ++ct){
    short8 w0 = lds8(Wf1b + ((size_t)(ct*16 + m) * 64 + g * 8));
    short8 w1 = lds8(Wf1b + ((size_t)(ct*16 + m) * 64 + g * 8 + 32));
    float4 b4 = *(const float4*)(bf1 + ct*16 + 4*g);
    f32x4 acc = {b4.x, b4.y, b4.z, b4.w};
    acc = __builtin_amdgcn_mfma_f32_16x16x32_bf16(w0, vb0, acc, 0, 0, 0);
    acc = __builtin_amdgcn_mfma_f32_16x16x32_bf16(w1, vb1, acc, 0, 0, 0);
    uint2 w;
    float g0 = 0.5f*acc[0]*(1.f + erff(acc[0]*0.70710678118654752f));
    float g1 = 0.5f*acc[1]*(1.f + erff(acc[1]*0.70710678118654752f));
    float g2 = 0.5f*acc[2]*(1.f + erff(acc[2]*0.70710678118654752f));
    float g3 = 0.5f*acc[3]*(1.f + erff(acc[3]*0.70710678118654752f));
    w.x = pk2(g0, g1); w.y = pk2(g2, g3);
    *(uint2*)&hs[wid][m * HSTR + ct*16 + 4*g] = w;
  }
  asm volatile("s_waitcnt lgkmcnt(0)" ::: "memory");
  short8 h0 = lds8(&hs[wid][m * HSTR + g * 8]);
  short8 h1 = lds8(&hs[wid][m * HSTR + g * 8 + 32]);

  float t[4][4];
  #pragma unroll
  for (int ct = 0; ct < 4; ++ct){
    short8 w0 = lds8(Wf2b + ((size_t)(ct*16 + m) * 64 + g * 8));
    short8 w1 = lds8(Wf2b + ((size_t)(ct*16 + m) * 64 + g * 8 + 32));
    float4 b4 = *(const float4*)(bf2 + ct*16 + 4*g);
    f32x4 acc = {b4.x, b4.y, b4.z, b4.w};
    acc = __builtin_amdgcn_mfma_f32_16x16x32_bf16(w0, h0, acc, 0, 0, 0);
    acc = __builtin_amdgcn_mfma_f32_16x16x32_bf16(w1, h1, acc, 0, 0, 0);
    float4 xr = *(const float4*)(x + (size_t)row * 64 + ct*16 + 4*g);
    t[ct][0] = acc[0] + xr.x; t[ct][1] = acc[1] + xr.y;
    t[ct][2] = acc[2] + xr.z; t[ct][3] = acc[3] + xr.w;
  }
  float s = 0.f;
  #pragma unroll
  for (int ct = 0; ct < 4; ++ct) s += (t[ct][0]+t[ct][1]) + (t[ct][2]+t[ct][3]);
  s += __shfl_xor(s, 16, 64); s += __shfl_xor(s, 32, 64);
  float mu = s * (1.f/64.f);
  float v = 0.f;
  #pragma unroll
  for (int ct = 0; ct < 4; ++ct){
    #pragma unroll
    for (int rg = 0; rg < 4; ++rg){ float d = t[ct][rg] - mu; v += d*d; }
  }
  v += __shfl_xor(v, 16, 64); v += __shfl_xor(v, 32, 64);
  float rs = rsqrtf(v * (1.f/64.f) + 1e-5f);
  #pragma unroll
  for (int ct = 0; ct < 4; ++ct){
    float4 g4 = *(const float4*)(g_ln + ct*16 + 4*g);
    float4 bb = *(const float4*)(b_ln + ct*16 + 4*g);
    float4 o;
    o.x = g4.x*(t[ct][0]-mu)*rs + bb.x;
    o.y = g4.y*(t[ct][1]-mu)*rs + bb.y;
    o.z = g4.z*(t[ct][2]-mu)*rs + bb.z;
    o.w = g4.w*(t[ct][3]-mu)*rs + bb.w;
    *(float4*)(out + (size_t)row * 64 + ct*16 + 4*g) = o;
  }
}

extern "C" void kernel_launch(void* const* d_in, const int* in_sizes, int n_in,
                              void* d_out, int out_size, void* d_ws, size_t ws_size,
                              hipStream_t stream) {
  const float* x    = (const float*)d_in[0];
  const float* A    = (const float*)d_in[1];
  const float* AT   = (const float*)d_in[2];
  const float* Wq   = (const float*)d_in[3];
  const float* bq   = (const float*)d_in[4];
  const float* Wk   = (const float*)d_in[5];
  const float* bk   = (const float*)d_in[6];
  const float* Wks  = (const float*)d_in[7];
  const float* bks  = (const float*)d_in[8];
  const float* Wv   = (const float*)d_in[9];
  const float* bv   = (const float*)d_in[10];
  const float* Wvs  = (const float*)d_in[11];
  const float* bvs  = (const float*)d_in[12];
  const float* Wdi  = (const float*)d_in[13];
  const float* Wdo  = (const float*)d_in[14];
  const float* Wf1  = (const float*)d_in[15];
  const float* bf1  = (const float*)d_in[16];
  const float* Wf2  = (const float*)d_in[17];
  const float* bf2  = (const float*)d_in[18];
  const float* g_ln = (const float*)d_in[19];
  const float* b_ln = (const float*)d_in[20];
  float* out = (float*)d_out;

  float* ws = (float*)d_ws;
  ushort* proj  = (ushort*)ws;                     // 12 slots (Q,KS,VS): 11,980,800 ush
  float*  biasF = ws + 5990400;                    // 473,088 f [4][21][11][4][16][8]
  ushort* val   = (ushort*)(ws + 6463488);         // 3,993,600 ush
  ushort* vt    = (ushort*)(ws + 8460288);         // 4,325,376 ush [4][192][11][16][32]
  ushort* kperm = (ushort*)(ws + 10622976);        // 4,325,376 ush [4][192][11][2][16][16]
  ushort* Wcat  = (ushort*)(ws + 12785664);        // 28,672 ush
  float*  bcat  = ws + 12800000;                   // 320 f
  ushort* Wf1b  = Wcat + 320*64;
  ushort* Wf2b  = Wcat + 384*64;

  wpack_kernel<<<7, 256, 0, stream>>>(Wq, bq, Wk, bk, Wks, bks,
                                      Wv, bv, Wvs, bvs, Wf1, Wf2, Wcat, bcat);
  prep_kernel<<<NPROJ + NBIAS + NPAD, 256, 0, stream>>>(
      x, Wcat, bcat, proj, vt, kperm, Wdi, Wdo, A, AT, biasF);
  attn_kernel<<<ANB, 256, 0, stream>>>(proj, biasF, vt, kperm, val);
  ffn_kernel<<<975, 256, 0, stream>>>(val, x, Wf1b, bf1, Wf2b, bf2,
                                      g_ln, b_ln, out);
}